// Round 8
// baseline (460.029 us; speedup 1.0000x reference)
//
#include <hip/hip_runtime.h>
#include <cmath>

#define IN_CH 128
#define AL(p) __hip_atomic_load((p), __ATOMIC_RELAXED, __HIP_MEMORY_SCOPE_AGENT)

typedef unsigned long long ull;
typedef ull  ull2 __attribute__((ext_vector_type(2)));
typedef float f4  __attribute__((ext_vector_type(4)));

// Monotone descending key: smaller key == higher norm; ties -> smaller edge idx
// (matches stable argsort of -norm). All keys distinct. Low 32 bits = edge idx.
__device__ __forceinline__ ull make_key(float norm, int e) {
    unsigned int b = __float_as_uint(norm);
    unsigned int asc = (b & 0x80000000u) ? ~b : (b | 0x80000000u); // monotone-increasing map
    unsigned int desc = ~asc;
    return (((ull)desc) << 32) | (unsigned int)e;
}

// One wave per node: p[n] = dot(x[n], w_src), q[n] = dot(x[n], w_dst), double accum.
// Per-node state init folded in.
__global__ void proj_kernel(const float* __restrict__ x, const float* __restrict__ w_src,
                            const float* __restrict__ w_dst, float* __restrict__ p,
                            float* __restrict__ q,
                            unsigned int* __restrict__ node_max, double* __restrict__ denom,
                            ull* __restrict__ wsuit, int* __restrict__ deg,
                            int* __restrict__ cluster, int* __restrict__ partner,
                            float* __restrict__ s_rep, int* __restrict__ bump, int N) {
    int gtid = blockIdx.x * blockDim.x + threadIdx.x;
    if (gtid == 0) *bump = 0;
    if (gtid < N) {
        node_max[gtid] = 0u;       // bits of +0.0f; any positive score has bits > 0
        denom[gtid]    = 0.0;
        wsuit[gtid]    = ~0ULL;
        deg[gtid]      = 0;
        cluster[gtid]  = gtid;
        partner[gtid]  = gtid;
        s_rep[gtid]    = 1.0f;
    }
    int wave = gtid >> 6;
    int lane = threadIdx.x & 63;
    if (wave >= N) return;
    float2 xv = ((const float2*)(x + (size_t)wave * IN_CH))[lane];
    float2 ws = ((const float2*)w_src)[lane];
    float2 wd = ((const float2*)w_dst)[lane];
    double ap = (double)xv.x * (double)ws.x + (double)xv.y * (double)ws.y;
    double aq = (double)xv.x * (double)wd.x + (double)xv.y * (double)wd.y;
    #pragma unroll
    for (int off = 32; off > 0; off >>= 1) {
        ap += __shfl_down(ap, off);
        aq += __shfl_down(aq, off);
    }
    if (lane == 0) { p[wave] = (float)ap; q[wave] = (float)aq; }
}

// Fused: edge score + per-source max (softmax prep) + degree histogram + packed
// (row,col) for displacement chains / extract.
__global__ void score_kernel(const int* __restrict__ row, const int* __restrict__ col,
                             const float* __restrict__ p, const float* __restrict__ q,
                             const float* __restrict__ bptr, float* __restrict__ score,
                             unsigned int* __restrict__ node_max, int* __restrict__ deg,
                             int2* __restrict__ rc, int E) {
    int e = blockIdx.x * blockDim.x + threadIdx.x;
    if (e >= E) return;
    int u = row[e], v = col[e];
    rc[e] = make_int2(u, v);
    float s = p[u] + q[v] + bptr[0];
    score[e] = s;
    if (s > 0.0f) atomicMax(&node_max[u], __float_as_uint(s));
    if (u != v) {
        atomicAdd(&deg[u], 1);
        atomicAdd(&deg[v], 1);
    }
}

// Fused: per-edge exp + denom accumulation; per-node CSR segment allocation
// (order-free: segments need only be disjoint, not node-ordered).
__global__ void exp_alloc_kernel(const int* __restrict__ row, const float* __restrict__ score,
                                 const unsigned int* __restrict__ node_max,
                                 float* __restrict__ norm, double* __restrict__ denom,
                                 const int* __restrict__ deg, int* __restrict__ bump,
                                 int2* __restrict__ seg, int* __restrict__ cursor,
                                 int E, int N) {
    int i = blockIdx.x * blockDim.x + threadIdx.x;
    if (i < N) {
        int d = deg[i];
        int lo = atomicAdd(bump, d);
        seg[i] = make_int2(lo, lo + d);
        cursor[i] = lo;
    }
    if (i >= E) return;
    int u = row[i];
    unsigned int mb = node_max[u];
    float s = score[i];
    float ev = 0.0f;
    if (mb != 0u && s > 0.0f) {
        float m = __uint_as_float(mb);
        ev = (float)exp((double)(s - m));   // double exp ~correctly rounded
        atomicAdd(&denom[u], (double)ev);   // order-independent (double accum)
    }
    norm[i] = ev;
}

// Fused: finalize norm (exact f32 div + 0.5, same as ref) + key + CSR scatter.
// Adjacency entry = 16B {key, neighbor}; non-temporal store to stream past the
// L2 write-allocate path (scattered 16B stores never write-combine: R7 showed
// 4x line amplification, 106MB for 25.6MB payload).
__global__ void norm_csr_kernel(const int* __restrict__ row, const int* __restrict__ col,
                                const float* __restrict__ score,
                                const unsigned int* __restrict__ node_max,
                                const double* __restrict__ denom, float* __restrict__ norm,
                                int* __restrict__ cursor, ull2* __restrict__ adj,
                                int E) {
    int e = blockIdx.x * blockDim.x + threadIdx.x;
    if (e >= E) return;
    int u = row[e], v = col[e];
    unsigned int mb = node_max[u];
    float nv;
    if (mb != 0u) {
        float s = score[e];
        if (s > 0.0f) {
            float d = (float)denom[u];
            nv = norm[e] / d + 0.5f;        // exact f32 div + add, same as ref
        } else {
            nv = 0.0f;
        }
    } else {
        nv = score[e];                       // raw score for rows with no positive edge
    }
    norm[e] = nv;
    if (u != v) {
        ull k = make_key(nv, e);
        ull2 eu; eu.x = k; eu.y = (ull)v;
        ull2 ev2; ev2.x = k; ev2.y = (ull)u;
        int pu = atomicAdd(&cursor[u], 1);
        __builtin_nontemporal_store(eu, &adj[pu]);
        int pv = atomicAdd(&cursor[v], 1);
        __builtin_nontemporal_store(ev2, &adj[pv]);
    }
}

// ---- Suitor matching (Manne-Bisseling), 32-lane-group-per-node (avg degree
// ~32: full wave was half idle). Exact greedy matching for distinct keys.
// ws[v] monotone-decreasing => stale reads are stale-high => failures retry.
__global__ void suitor_kernel(const int2* __restrict__ seg,
                              const ull2* __restrict__ adj,
                              const int2* __restrict__ rc,
                              ull* __restrict__ ws, int N) {
    int grp  = (blockIdx.x * blockDim.x + threadIdx.x) >> 5;
    int lane = threadIdx.x & 31;
    if (grp >= N) return;
    int cur = grp;
    for (int guard = 0; guard < 1000000; ++guard) {
        int2 lohi = seg[cur];
        ull bk = ~0ULL;
        int bv = -1;
        for (int i = lohi.x + lane; i < lohi.y; i += 32) {
            ull2 ent = adj[i];              // coalesced 16B
            ull k = ent.x;
            if (k < bk) {
                int v = (int)ent.y;
                if (k < AL(&ws[v])) { bk = k; bv = v; }
            }
        }
        // group-wide butterfly min-reduce with payload (width 32)
        #pragma unroll
        for (int off = 16; off > 0; off >>= 1) {
            ull ok = __shfl_xor(bk, off, 32);
            int ov = __shfl_xor(bv, off, 32);
            if (ok < bk) { bk = ok; bv = ov; }
        }
        if (bk == ~0ULL) break;             // no feasible proposal: cur stays unmatched
        ull old;
        if (lane == 0) old = atomicMin(&ws[bv], bk);
        old = __shfl(old, 0, 32);
        if (old > bk) {
            // accepted; take over the displaced proposer (atomicMin hands each
            // displaced value to exactly one group)
            if (old == ~0ULL) break;
            int e = (int)(old & 0xffffffffu);
            int2 pr = rc[e];                // same address across group -> broadcast
            cur = pr.x ^ pr.y ^ bv;         // displaced proposer = other endpoint of e
        }
        // else: beaten concurrently (ws[bv] already <= bk) -> rescan same cur
    }
}

// Node-centric extract: each node's standing proposal names its edge; matched
// iff mutual (ws[a]==ws[b]==k). The a-side thread writes (once per pair).
__global__ void extract_kernel(const int2* __restrict__ rc, const float* __restrict__ norm,
                               const ull* __restrict__ ws,
                               int* __restrict__ cluster, int* __restrict__ partner,
                               float* __restrict__ s_rep, int N) {
    int w = blockIdx.x * blockDim.x + threadIdx.x;
    if (w >= N) return;
    ull k = ws[w];
    if (k == ~0ULL) return;
    int e = (int)(k & 0xffffffffu);
    int2 pr = rc[e];                        // w is an endpoint of e
    int a = pr.x, b = pr.y;
    if (w != a) return;                     // b-side duplicate: skip
    if (ws[b] == k) {                       // mutual => matched (ws[a]==k by construction)
        cluster[b] = a;                     // b merged into rep a (ref: cluster[c_s]=r_s)
        partner[a] = b;
        s_rep[a]   = norm[e];
    }
}

// Fused epilogue: blocks [0, NB1) do new_x/cluster/is_rep; blocks [NB1, ..) do edges.
// Pure-output streams use non-temporal stores (never re-read; keep L2 for gathers).
__global__ void out_kernel(const float* __restrict__ x, const int* __restrict__ cluster,
                           const int* __restrict__ partner, const float* __restrict__ s_rep,
                           const int* __restrict__ row, const int* __restrict__ col,
                           const float* __restrict__ w,
                           float* __restrict__ out_newx, float* __restrict__ out_cluster,
                           float* __restrict__ out_isrep, float* __restrict__ out_nrow,
                           float* __restrict__ out_ncol, float* __restrict__ out_valid,
                           float* __restrict__ out_w, int N, int E, int NB1) {
    if ((int)blockIdx.x < NB1) {
        int t = blockIdx.x * blockDim.x + threadIdx.x;
        if (t >= N * (IN_CH / 4)) return;
        int n = t >> 5;            // IN_CH/4 == 32 float4 per node
        int c = (t & 31) * 4;
        int cl = cluster[n];
        if ((t & 31) == 0) {
            __builtin_nontemporal_store((float)cl, &out_cluster[n]);
            __builtin_nontemporal_store((cl == n) ? 1.0f : 0.0f, &out_isrep[n]);
        }
        f4 o;
        int v = partner[n];
        if (cl != n) {
            o = (f4)0.0f;                                     // merged-away node row
        } else if (v != n) {
            float s = s_rep[n];
            f4 xu = *(const f4*)(x + (size_t)n * IN_CH + c);
            f4 xv = *(const f4*)(x + (size_t)v * IN_CH + c);
            o = (xu + xv) * s + xv;
        } else {
            o = *(const f4*)(x + (size_t)n * IN_CH + c);      // untouched node
        }
        __builtin_nontemporal_store(o, (f4*)out_newx + t);
    } else {
        int e = (blockIdx.x - NB1) * blockDim.x + threadIdx.x;
        if (e >= E) return;
        int nr = cluster[row[e]];
        int nc = cluster[col[e]];
        __builtin_nontemporal_store((float)nr, &out_nrow[e]);
        __builtin_nontemporal_store((float)nc, &out_ncol[e]);
        __builtin_nontemporal_store((nr != nc) ? 1.0f : 0.0f, &out_valid[e]);
        __builtin_nontemporal_store(w[e], &out_w[e]);
    }
}

extern "C" void kernel_launch(void* const* d_in, const int* in_sizes, int n_in_args,
                              void* d_out, int out_size, void* d_ws, size_t ws_size,
                              hipStream_t stream) {
    const float* x     = (const float*)d_in[0];
    const float* w_src = (const float*)d_in[1];
    const float* w_dst = (const float*)d_in[2];
    const float* bptr  = (const float*)d_in[3];
    const int*   ei    = (const int*)d_in[4];
    const float* ew    = (const float*)d_in[5];
    const int N = in_sizes[0] / IN_CH;
    const int E = in_sizes[5];
    const int* row = ei;
    const int* col = ei + E;

    char* wsb = (char*)d_ws;
    size_t off = 0;
    auto alloc = [&](size_t bytes) -> void* {
        off = (off + 255) & ~(size_t)255;
        void* ptr = wsb + off;
        off += bytes;
        return ptr;
    };
    float*        score    = (float*)alloc((size_t)E * 4);
    float*        norm     = (float*)alloc((size_t)E * 4);
    int2*         rc       = (int2*)alloc((size_t)E * 8);
    ull2*         adj      = (ull2*)alloc((size_t)2 * E * 16);
    unsigned int* node_max = (unsigned int*)alloc((size_t)N * 4);
    double*       denom    = (double*)alloc((size_t)N * 8);
    ull*          wsuit    = (ull*)alloc((size_t)N * 8);
    int*          deg      = (int*)alloc((size_t)N * 4);
    int2*         seg      = (int2*)alloc((size_t)N * 8);
    int*          cursor   = (int*)alloc((size_t)N * 4);
    int*          cluster  = (int*)alloc((size_t)N * 4);
    int*          partner  = (int*)alloc((size_t)N * 4);
    float*        s_rep    = (float*)alloc((size_t)N * 4);
    float*        pbuf     = (float*)alloc((size_t)N * 4);
    float*        qbuf     = (float*)alloc((size_t)N * 4);
    int*          bump     = (int*)alloc(64);

    // Output layout: new_x[N*128] | cluster[N] | is_rep[N] | new_row[E] | new_col[E] | edge_valid[E] | edge_weight[E]
    float* out       = (float*)d_out;
    float* o_newx    = out;
    float* o_cluster = out + (size_t)N * IN_CH;
    float* o_isrep   = o_cluster + N;
    float* o_nrow    = o_isrep + N;
    float* o_ncol    = o_nrow + E;
    float* o_valid   = o_ncol + E;
    float* o_w       = o_valid + E;

    const int T = 256;
    hipLaunchKernelGGL(proj_kernel, dim3((N * 64 + T - 1) / T), dim3(T), 0, stream,
                       x, w_src, w_dst, pbuf, qbuf,
                       node_max, denom, wsuit, deg, cluster, partner, s_rep, bump, N);
    hipLaunchKernelGGL(score_kernel, dim3((E + T - 1) / T), dim3(T), 0, stream,
                       row, col, pbuf, qbuf, bptr, score, node_max, deg, rc, E);
    hipLaunchKernelGGL(exp_alloc_kernel, dim3((E + T - 1) / T), dim3(T), 0, stream,
                       row, score, node_max, norm, denom, deg, bump, seg, cursor, E, N);
    hipLaunchKernelGGL(norm_csr_kernel, dim3((E + T - 1) / T), dim3(T), 0, stream,
                       row, col, score, node_max, denom, norm, cursor, adj, E);
    hipLaunchKernelGGL(suitor_kernel, dim3((N * 32 + T - 1) / T), dim3(T), 0, stream,
                       seg, adj, rc, wsuit, N);
    hipLaunchKernelGGL(extract_kernel, dim3((N + T - 1) / T), dim3(T), 0, stream,
                       rc, norm, wsuit, cluster, partner, s_rep, N);
    const int NB1 = (N * 32 + T - 1) / T;
    const int NB2 = (E + T - 1) / T;
    hipLaunchKernelGGL(out_kernel, dim3(NB1 + NB2), dim3(T), 0, stream,
                       x, cluster, partner, s_rep, row, col, ew,
                       o_newx, o_cluster, o_isrep, o_nrow, o_ncol, o_valid, o_w, N, E, NB1);
    (void)ws_size; (void)out_size; (void)n_in_args;
}

// Round 9
// 417.156 us; speedup vs baseline: 1.1028x; 1.1028x over previous
//
#include <hip/hip_runtime.h>
#include <cmath>

#define IN_CH 128
#define AL(p) __hip_atomic_load((p), __ATOMIC_RELAXED, __HIP_MEMORY_SCOPE_AGENT)

typedef unsigned long long ull;
typedef ull  ull2 __attribute__((ext_vector_type(2)));
typedef float f4  __attribute__((ext_vector_type(4)));

// Monotone descending key: smaller key == higher norm; ties -> smaller edge idx
// (matches stable argsort of -norm). All keys distinct. Low 32 bits = edge idx.
__device__ __forceinline__ ull make_key(float norm, int e) {
    unsigned int b = __float_as_uint(norm);
    unsigned int asc = (b & 0x80000000u) ? ~b : (b | 0x80000000u); // monotone-increasing map
    unsigned int desc = ~asc;
    return (((ull)desc) << 32) | (unsigned int)e;
}

// One wave per node: p[n] = dot(x[n], w_src), q[n] = dot(x[n], w_dst), double accum.
// Per-node state init + counter zeroing folded in.
__global__ void proj_kernel(const float* __restrict__ x, const float* __restrict__ w_src,
                            const float* __restrict__ w_dst, float* __restrict__ p,
                            float* __restrict__ q,
                            unsigned int* __restrict__ node_max, double* __restrict__ denom,
                            ull* __restrict__ wsuit, int* __restrict__ deg,
                            int* __restrict__ cluster, int* __restrict__ partner,
                            float* __restrict__ s_rep, int* __restrict__ bump,
                            int* __restrict__ btail, int N) {
    int gtid = blockIdx.x * blockDim.x + threadIdx.x;
    if (gtid == 0) *bump = 0;
    if (gtid < 8) btail[gtid] = 0;
    if (gtid < N) {
        node_max[gtid] = 0u;       // bits of +0.0f; any positive score has bits > 0
        denom[gtid]    = 0.0;
        wsuit[gtid]    = ~0ULL;
        deg[gtid]      = 0;
        cluster[gtid]  = gtid;
        partner[gtid]  = gtid;
        s_rep[gtid]    = 1.0f;
    }
    int wave = gtid >> 6;
    int lane = threadIdx.x & 63;
    if (wave >= N) return;
    float2 xv = ((const float2*)(x + (size_t)wave * IN_CH))[lane];
    float2 ws = ((const float2*)w_src)[lane];
    float2 wd = ((const float2*)w_dst)[lane];
    double ap = (double)xv.x * (double)ws.x + (double)xv.y * (double)ws.y;
    double aq = (double)xv.x * (double)wd.x + (double)xv.y * (double)wd.y;
    #pragma unroll
    for (int off = 32; off > 0; off >>= 1) {
        ap += __shfl_down(ap, off);
        aq += __shfl_down(aq, off);
    }
    if (lane == 0) { p[wave] = (float)ap; q[wave] = (float)aq; }
}

// Fused: edge score + per-source max + degree histogram + rc pack + XCD-bucket
// build (entry = edge id | side flag<<30; bucket = endpoint-node & 7).
// Block-aggregated bucket tails: 8 global atomics per block.
__global__ void score_kernel(const int* __restrict__ row, const int* __restrict__ col,
                             const float* __restrict__ p, const float* __restrict__ q,
                             const float* __restrict__ bptr, float* __restrict__ score,
                             unsigned int* __restrict__ node_max, int* __restrict__ deg,
                             int2* __restrict__ rc, int* __restrict__ btail,
                             unsigned int* __restrict__ bucket, int bcap, int E) {
    __shared__ int cnt[8];
    __shared__ int gbase[8];
    int e = blockIdx.x * blockDim.x + threadIdx.x;
    if (threadIdx.x < 8) cnt[threadIdx.x] = 0;
    __syncthreads();
    bool inb = e < E;
    int u = 0, v = 0, l1 = -1, l2 = -1, h1 = 0, h2 = 0;
    if (inb) {
        u = row[e]; v = col[e];
        rc[e] = make_int2(u, v);
        float s = p[u] + q[v] + bptr[0];
        score[e] = s;
        if (s > 0.0f) atomicMax(&node_max[u], __float_as_uint(s));
        if (u != v) {
            atomicAdd(&deg[u], 1);
            atomicAdd(&deg[v], 1);
            h1 = u & 7; l1 = atomicAdd(&cnt[h1], 1);
            h2 = v & 7; l2 = atomicAdd(&cnt[h2], 1);
        }
    }
    __syncthreads();
    if (threadIdx.x < 8) gbase[threadIdx.x] = atomicAdd(&btail[threadIdx.x], cnt[threadIdx.x]);
    __syncthreads();
    if (l1 >= 0) bucket[(size_t)h1 * bcap + gbase[h1] + l1] = (unsigned int)e;
    if (l2 >= 0) bucket[(size_t)h2 * bcap + gbase[h2] + l2] = (unsigned int)e | (1u << 30);
}

// Fused: per-edge exp + denom accumulation; per-node CSR segment allocation,
// PADDED to 64B (4-entry) multiples so no adj line spans two nodes (XCD-local
// write requirement). Order-free bump allocation.
__global__ void exp_alloc_kernel(const int* __restrict__ row, const float* __restrict__ score,
                                 const unsigned int* __restrict__ node_max,
                                 float* __restrict__ norm, double* __restrict__ denom,
                                 const int* __restrict__ deg, int* __restrict__ bump,
                                 int2* __restrict__ seg, int* __restrict__ cursor,
                                 int E, int N) {
    int i = blockIdx.x * blockDim.x + threadIdx.x;
    if (i < N) {
        int d = deg[i];
        int lo = atomicAdd(bump, (d + 3) & ~3);   // 64B-aligned segments
        seg[i] = make_int2(lo, lo + d);
        cursor[i] = lo;
    }
    if (i >= E) return;
    int u = row[i];
    unsigned int mb = node_max[u];
    float s = score[i];
    float ev = 0.0f;
    if (mb != 0u && s > 0.0f) {
        float m = __uint_as_float(mb);
        ev = (float)exp((double)(s - m));   // double exp ~correctly rounded
        atomicAdd(&denom[u], (double)ev);   // order-independent (double accum)
    }
    norm[i] = ev;
}

// Phase A: finalize norm (exact f32 div + 0.5, same as ref) + coalesced key write.
__global__ void norm_key_kernel(const int* __restrict__ row, const float* __restrict__ score,
                                const unsigned int* __restrict__ node_max,
                                const double* __restrict__ denom, float* __restrict__ norm,
                                ull* __restrict__ keyn, int E) {
    int e = blockIdx.x * blockDim.x + threadIdx.x;
    if (e >= E) return;
    int u = row[e];
    unsigned int mb = node_max[u];
    float nv;
    if (mb != 0u) {
        float s = score[e];
        if (s > 0.0f) {
            float d = (float)denom[u];
            nv = norm[e] / d + 0.5f;        // exact f32 div + add, same as ref
        } else {
            nv = 0.0f;
        }
    } else {
        nv = score[e];                       // raw score for rows with no positive edge
    }
    norm[e] = nv;
    keyn[e] = make_key(nv, e);
}

// Phase B: XCD-pinned CSR scatter. blockIdx&7 ~ XCD (round-robin dispatch
// heuristic; wrong mapping costs speed only). All writers of a node's (line-
// aligned) segment share one XCD -> each adj line written back once, full.
__global__ void csr_scatter_kernel(const unsigned int* __restrict__ bucket,
                                   const int* __restrict__ btail, int bcap,
                                   const ull* __restrict__ keyn, const int2* __restrict__ rc,
                                   int* __restrict__ cursor, ull2* __restrict__ adj, int bpx) {
    int xcd = blockIdx.x & 7;
    int sub = blockIdx.x >> 3;
    int n = btail[xcd];
    const unsigned int* bk = bucket + (size_t)xcd * bcap;
    for (int i = sub * blockDim.x + threadIdx.x; i < n; i += bpx * blockDim.x) {
        unsigned int ent = bk[i];
        int e = (int)(ent & 0x3fffffffu);
        int2 pr = rc[e];
        int side = (int)(ent >> 30);
        int dst = side ? pr.y : pr.x;
        int nb  = side ? pr.x : pr.y;
        ull k = keyn[e];
        int pos = atomicAdd(&cursor[dst], 1);
        ull2 w; w.x = k; w.y = (ull)nb;
        adj[pos] = w;
    }
}

// ---- Suitor matching (Manne-Bisseling), 32-lane-group-per-node (avg degree
// ~32). Exact greedy matching for distinct keys. ws[v] monotone-decreasing =>
// stale reads are stale-high => failures retry.
__global__ void suitor_kernel(const int2* __restrict__ seg,
                              const ull2* __restrict__ adj,
                              const int2* __restrict__ rc,
                              ull* __restrict__ ws, int N) {
    int grp  = (blockIdx.x * blockDim.x + threadIdx.x) >> 5;
    int lane = threadIdx.x & 31;
    if (grp >= N) return;
    int cur = grp;
    for (int guard = 0; guard < 1000000; ++guard) {
        int2 lohi = seg[cur];
        ull bk = ~0ULL;
        int bv = -1;
        for (int i = lohi.x + lane; i < lohi.y; i += 32) {
            ull2 ent = adj[i];              // coalesced 16B
            ull k = ent.x;
            if (k < bk) {
                int v = (int)ent.y;
                if (k < AL(&ws[v])) { bk = k; bv = v; }
            }
        }
        // group-wide butterfly min-reduce with payload (width 32)
        #pragma unroll
        for (int off = 16; off > 0; off >>= 1) {
            ull ok = __shfl_xor(bk, off, 32);
            int ov = __shfl_xor(bv, off, 32);
            if (ok < bk) { bk = ok; bv = ov; }
        }
        if (bk == ~0ULL) break;             // no feasible proposal: cur stays unmatched
        ull old;
        if (lane == 0) old = atomicMin(&ws[bv], bk);
        old = __shfl(old, 0, 32);
        if (old > bk) {
            // accepted; take over the displaced proposer (atomicMin hands each
            // displaced value to exactly one group)
            if (old == ~0ULL) break;
            int e = (int)(old & 0xffffffffu);
            int2 pr = rc[e];                // same address across group -> broadcast
            cur = pr.x ^ pr.y ^ bv;         // displaced proposer = other endpoint of e
        }
        // else: beaten concurrently (ws[bv] already <= bk) -> rescan same cur
    }
}

// Node-centric extract: each node's standing proposal names its edge; matched
// iff mutual (ws[a]==ws[b]==k). The a-side thread writes (once per pair).
__global__ void extract_kernel(const int2* __restrict__ rc, const float* __restrict__ norm,
                               const ull* __restrict__ ws,
                               int* __restrict__ cluster, int* __restrict__ partner,
                               float* __restrict__ s_rep, int N) {
    int w = blockIdx.x * blockDim.x + threadIdx.x;
    if (w >= N) return;
    ull k = ws[w];
    if (k == ~0ULL) return;
    int e = (int)(k & 0xffffffffu);
    int2 pr = rc[e];                        // w is an endpoint of e
    int a = pr.x, b = pr.y;
    if (w != a) return;                     // b-side duplicate: skip
    if (ws[b] == k) {                       // mutual => matched (ws[a]==k by construction)
        cluster[b] = a;                     // b merged into rep a (ref: cluster[c_s]=r_s)
        partner[a] = b;
        s_rep[a]   = norm[e];
    }
}

// Fused epilogue: blocks [0, NB1) do new_x/cluster/is_rep; blocks [NB1, ..) do
// edges. nt ONLY on the fully-coalesced f4 newx stream (R8 lesson: nt on
// scattered/partial-line stores = DRAM RMW, regression).
__global__ void out_kernel(const float* __restrict__ x, const int* __restrict__ cluster,
                           const int* __restrict__ partner, const float* __restrict__ s_rep,
                           const int* __restrict__ row, const int* __restrict__ col,
                           const float* __restrict__ w,
                           float* __restrict__ out_newx, float* __restrict__ out_cluster,
                           float* __restrict__ out_isrep, float* __restrict__ out_nrow,
                           float* __restrict__ out_ncol, float* __restrict__ out_valid,
                           float* __restrict__ out_w, int N, int E, int NB1) {
    if ((int)blockIdx.x < NB1) {
        int t = blockIdx.x * blockDim.x + threadIdx.x;
        if (t >= N * (IN_CH / 4)) return;
        int n = t >> 5;            // IN_CH/4 == 32 float4 per node
        int c = (t & 31) * 4;
        int cl = cluster[n];
        if ((t & 31) == 0) {
            out_cluster[n] = (float)cl;
            out_isrep[n]   = (cl == n) ? 1.0f : 0.0f;
        }
        f4 o;
        int v = partner[n];
        if (cl != n) {
            o = (f4)0.0f;                                     // merged-away node row
        } else if (v != n) {
            float s = s_rep[n];
            f4 xu = *(const f4*)(x + (size_t)n * IN_CH + c);
            f4 xv = *(const f4*)(x + (size_t)v * IN_CH + c);
            o = (xu + xv) * s + xv;
        } else {
            o = *(const f4*)(x + (size_t)n * IN_CH + c);      // untouched node
        }
        __builtin_nontemporal_store(o, (f4*)out_newx + t);
    } else {
        int e = (blockIdx.x - NB1) * blockDim.x + threadIdx.x;
        if (e >= E) return;
        int nr = cluster[row[e]];
        int nc = cluster[col[e]];
        out_nrow[e]  = (float)nr;
        out_ncol[e]  = (float)nc;
        out_valid[e] = (nr != nc) ? 1.0f : 0.0f;
        out_w[e]     = w[e];
    }
}

extern "C" void kernel_launch(void* const* d_in, const int* in_sizes, int n_in_args,
                              void* d_out, int out_size, void* d_ws, size_t ws_size,
                              hipStream_t stream) {
    const float* x     = (const float*)d_in[0];
    const float* w_src = (const float*)d_in[1];
    const float* w_dst = (const float*)d_in[2];
    const float* bptr  = (const float*)d_in[3];
    const int*   ei    = (const int*)d_in[4];
    const float* ew    = (const float*)d_in[5];
    const int N = in_sizes[0] / IN_CH;
    const int E = in_sizes[5];
    const int* row = ei;
    const int* col = ei + E;

    char* wsb = (char*)d_ws;
    size_t off = 0;
    auto alloc = [&](size_t bytes) -> void* {
        off = (off + 255) & ~(size_t)255;
        void* ptr = wsb + off;
        off += bytes;
        return ptr;
    };
    const int bcap = E / 4 + (E >> 6) + 1024;   // per-bucket capacity (2E/8 + slack)
    float*        score    = (float*)alloc((size_t)E * 4);
    float*        norm     = (float*)alloc((size_t)E * 4);
    int2*         rc       = (int2*)alloc((size_t)E * 8);
    ull*          keyn     = (ull*)alloc((size_t)E * 8);
    ull2*         adj      = (ull2*)alloc(((size_t)2 * E + 4 * N) * 16);
    unsigned int* bucket   = (unsigned int*)alloc((size_t)8 * bcap * 4);
    unsigned int* node_max = (unsigned int*)alloc((size_t)N * 4);
    double*       denom    = (double*)alloc((size_t)N * 8);
    ull*          wsuit    = (ull*)alloc((size_t)N * 8);
    int*          deg      = (int*)alloc((size_t)N * 4);
    int2*         seg      = (int2*)alloc((size_t)N * 8);
    int*          cursor   = (int*)alloc((size_t)N * 4);
    int*          cluster  = (int*)alloc((size_t)N * 4);
    int*          partner  = (int*)alloc((size_t)N * 4);
    float*        s_rep    = (float*)alloc((size_t)N * 4);
    float*        pbuf     = (float*)alloc((size_t)N * 4);
    float*        qbuf     = (float*)alloc((size_t)N * 4);
    int*          bump     = (int*)alloc(64);
    int*          btail    = (int*)alloc(64);

    // Output layout: new_x[N*128] | cluster[N] | is_rep[N] | new_row[E] | new_col[E] | edge_valid[E] | edge_weight[E]
    float* out       = (float*)d_out;
    float* o_newx    = out;
    float* o_cluster = out + (size_t)N * IN_CH;
    float* o_isrep   = o_cluster + N;
    float* o_nrow    = o_isrep + N;
    float* o_ncol    = o_nrow + E;
    float* o_valid   = o_ncol + E;
    float* o_w       = o_valid + E;

    const int T = 256;
    hipLaunchKernelGGL(proj_kernel, dim3((N * 64 + T - 1) / T), dim3(T), 0, stream,
                       x, w_src, w_dst, pbuf, qbuf,
                       node_max, denom, wsuit, deg, cluster, partner, s_rep, bump, btail, N);
    hipLaunchKernelGGL(score_kernel, dim3((E + T - 1) / T), dim3(T), 0, stream,
                       row, col, pbuf, qbuf, bptr, score, node_max, deg, rc,
                       btail, bucket, bcap, E);
    hipLaunchKernelGGL(exp_alloc_kernel, dim3((E + T - 1) / T), dim3(T), 0, stream,
                       row, score, node_max, norm, denom, deg, bump, seg, cursor, E, N);
    hipLaunchKernelGGL(norm_key_kernel, dim3((E + T - 1) / T), dim3(T), 0, stream,
                       row, score, node_max, denom, norm, keyn, E);
    const int bpx = 40;                     // blocks per XCD slot
    hipLaunchKernelGGL(csr_scatter_kernel, dim3(8 * bpx), dim3(T), 0, stream,
                       bucket, btail, bcap, keyn, rc, cursor, adj, bpx);
    hipLaunchKernelGGL(suitor_kernel, dim3((N * 32 + T - 1) / T), dim3(T), 0, stream,
                       seg, adj, rc, wsuit, N);
    hipLaunchKernelGGL(extract_kernel, dim3((N + T - 1) / T), dim3(T), 0, stream,
                       rc, norm, wsuit, cluster, partner, s_rep, N);
    const int NB1 = (N * 32 + T - 1) / T;
    const int NB2 = (E + T - 1) / T;
    hipLaunchKernelGGL(out_kernel, dim3(NB1 + NB2), dim3(T), 0, stream,
                       x, cluster, partner, s_rep, row, col, ew,
                       o_newx, o_cluster, o_isrep, o_nrow, o_ncol, o_valid, o_w, N, E, NB1);
    (void)ws_size; (void)out_size; (void)n_in_args;
}